// Round 3
// baseline (747.532 us; speedup 1.0000x reference)
//
#include <hip/hip_runtime.h>
#include <hip/hip_bf16.h>

#define DD 256
#define ROWS 64
#define BSTRIDE 264   // bf16 elements per row in x/msg LDS tile (528 B, 16B-aligned)

typedef __attribute__((ext_vector_type(8))) short bf16x8;
typedef __attribute__((ext_vector_type(4))) float f32x4;

__device__ __forceinline__ ushort f2bf(float f) {
    unsigned u = __float_as_uint(f);
    u += 0x7fffu + ((u >> 16) & 1u);
    return (ushort)(u >> 16);
}
__device__ __forceinline__ float bf2f(ushort h) {
    return __uint_as_float(((unsigned)h) << 16);
}

__device__ __forceinline__ float mish_f(float t) {
    float u = __expf(t);
    float w = u * (u + 2.0f);
    float r = t * (w / (w + 2.0f));
    return (t > 15.0f) ? t : r;
}

// Stage up to 64 rows x 256 cols fp32 -> bf16 LDS, XOR-swizzled (row*512 + (kbyte ^ ((row&7)<<4))).
__device__ __forceinline__ void stage_rows(const float* __restrict__ src,
                                           int rowsValid, char* lds) {
    const int t = threadIdx.x;
#pragma unroll
    for (int i = 0; i < 16; ++i) {
        int c = i * 256 + t;
        int row = c >> 6;
        int col4 = (c & 63) << 2;
        float4 v = make_float4(0.f, 0.f, 0.f, 0.f);
        if (row < rowsValid)
            v = *(const float4*)(src + (size_t)row * DD + col4);
        ushort4 h;
        h.x = f2bf(v.x); h.y = f2bf(v.y); h.z = f2bf(v.z); h.w = f2bf(v.w);
        int off = row * 512 + ((col4 * 2) ^ ((row & 7) << 4));
        *(ushort4*)(lds + off) = h;
    }
}

// Same but rows gathered via perm (row ids in LDS array permRow).
__device__ __forceinline__ void stage_rows_perm(const float* __restrict__ src,
                                                const int* permRow, int rowsValid,
                                                char* lds) {
    const int t = threadIdx.x;
#pragma unroll
    for (int i = 0; i < 16; ++i) {
        int c = i * 256 + t;
        int row = c >> 6;
        int col4 = (c & 63) << 2;
        float4 v = make_float4(0.f, 0.f, 0.f, 0.f);
        if (row < rowsValid)
            v = *(const float4*)(src + (size_t)permRow[row] * DD + col4);
        ushort4 h;
        h.x = f2bf(v.x); h.y = f2bf(v.y); h.z = f2bf(v.z); h.w = f2bf(v.w);
        int off = row * 512 + ((col4 * 2) ^ ((row & 7) << 4));
        *(ushort4*)(lds + off) = h;
    }
}

// 64x256 @ W^T (256x256): 4 waves x 16 rows. A: row=lane&15, k=(lane>>4)*8+j.
__device__ __forceinline__ void gemm_core(const char* lds, const ushort* __restrict__ Wbf,
                                          f32x4 acc[16]) {
    const int lane = threadIdx.x & 63;
    const int wave = threadIdx.x >> 6;
    const int r = lane & 15;
    const int halfk = lane >> 4;
    const int row = wave * 16 + r;
    bf16x8 afr[8];
#pragma unroll
    for (int ks = 0; ks < 8; ++ks) {
        int kbyte = ks * 64 + halfk * 16;
        afr[ks] = *(const bf16x8*)(lds + row * 512 + (kbyte ^ ((row & 7) << 4)));
    }
#pragma unroll
    for (int ct = 0; ct < 16; ++ct) {
        const ushort* wrow = Wbf + (size_t)(ct * 16 + r) * DD + halfk * 8;
#pragma unroll
        for (int ks = 0; ks < 8; ++ks) {
            bf16x8 bfr = *(const bf16x8*)(wrow + ks * 32);
            acc[ct] = __builtin_amdgcn_mfma_f32_16x16x32_bf16(afr[ks], bfr, acc[ct], 0, 0, 0);
        }
    }
}

__global__ void __launch_bounds__(256) convert_w_kernel(const float* __restrict__ in,
                                                        ushort* __restrict__ out, int n4) {
    int i = blockIdx.x * blockDim.x + threadIdx.x;
    if (i < n4) {
        float4 v = ((const float4*)in)[i];
        ushort4 h;
        h.x = f2bf(v.x); h.y = f2bf(v.y); h.z = f2bf(v.z); h.w = f2bf(v.w);
        ((ushort4*)out)[i] = h;
    }
}

__global__ void __launch_bounds__(256) zero_kernel(int* __restrict__ p, int n) {
    int i = blockIdx.x * blockDim.x + threadIdx.x;
    if (i < n) p[i] = 0;
}

__global__ void __launch_bounds__(256) hist_kernel(const int* __restrict__ dst,
                                                   int* __restrict__ h, int E) {
    int e = blockIdx.x * blockDim.x + threadIdx.x;
    if (e < E) atomicAdd(&h[dst[e]], 1);
}

// Single-block exclusive scan: h[0..n) -> h2[0..n)
__global__ void __launch_bounds__(256) scan_kernel(const int* __restrict__ h,
                                                   int* __restrict__ h2, int n) {
    __shared__ int wsum[4];
    __shared__ int carry_s;
    if (threadIdx.x == 0) carry_s = 0;
    const int lane = threadIdx.x & 63;
    const int wave = threadIdx.x >> 6;
    for (int base = 0; base < n; base += 256) {
        int i = base + threadIdx.x;
        int v = (i < n) ? h[i] : 0;
        int s = v;
#pragma unroll
        for (int off = 1; off < 64; off <<= 1) {
            int u = __shfl_up(s, off, 64);
            if (lane >= off) s += u;
        }
        __syncthreads();             // prev iteration's consumers done; carry updated
        if (lane == 63) wsum[wave] = s;
        __syncthreads();
        int prefix = carry_s;
        for (int wv = 0; wv < wave; ++wv) prefix += wsum[wv];
        if (i < n) h2[i] = prefix + s - v;   // exclusive
        __syncthreads();
        if (threadIdx.x == 0) carry_s += wsum[0] + wsum[1] + wsum[2] + wsum[3];
    }
}

// perm/src/dst in dst-sorted order; h2 holds segment starts (consumed).
__global__ void __launch_bounds__(256) scatter_kernel(const int* __restrict__ src,
                                                      const int* __restrict__ dst,
                                                      int* __restrict__ h2,
                                                      int* __restrict__ permS,
                                                      int* __restrict__ srcS,
                                                      int* __restrict__ dstS, int E) {
    int e = blockIdx.x * blockDim.x + threadIdx.x;
    if (e < E) {
        int d = dst[e];
        int pos = atomicAdd(&h2[d], 1);
        permS[pos] = e;
        srcS[pos] = src[e];
        dstS[pos] = d;
    }
}

// x = mish(node @ Wd^T + bd); write bf16 to xbf (ws) and f32 to agg (d_out)
__global__ void __launch_bounds__(256) node_kernel(const float* __restrict__ nf,
                                                   const ushort* __restrict__ Wd,
                                                   const float* __restrict__ bd,
                                                   ushort* __restrict__ xbf,
                                                   float* __restrict__ agg, int M) {
    __shared__ char lds[ROWS * 512];
    const int base = blockIdx.x * ROWS;
    const int rowsValid = min(ROWS, M - base);
    stage_rows(nf + (size_t)base * DD, rowsValid, lds);
    __syncthreads();
    f32x4 acc[16];
#pragma unroll
    for (int i = 0; i < 16; ++i) acc[i] = (f32x4){0.f, 0.f, 0.f, 0.f};
    gemm_core(lds, Wd, acc);
    const int lane = threadIdx.x & 63;
    const int wave = threadIdx.x >> 6;
    const int r = lane & 15, q = lane >> 4;
#pragma unroll
    for (int ct = 0; ct < 16; ++ct) {
        int col = ct * 16 + r;
        float bb = bd[col];
#pragma unroll
        for (int j = 0; j < 4; ++j) {
            int lrow = wave * 16 + q * 4 + j;
            if (lrow < rowsValid) {
                size_t idx = (size_t)(base + lrow) * DD + col;
                float m = mish_f(acc[ct][j] + bb);
                xbf[idx] = f2bf(m);
                agg[idx] = m;
            }
        }
    }
}

// Sorted-edge kernel: gather ef via perm, GEMM, msg = relu(x[src]+y) into LDS,
// run-reduce rows sharing dst, one atomicAdd per (run,col).
__global__ void __launch_bounds__(256) edge_kernel(const float* __restrict__ ef,
                                                   const ushort* __restrict__ We,
                                                   const float* __restrict__ be,
                                                   const ushort* __restrict__ xbf,
                                                   const int* __restrict__ permS,
                                                   const int* __restrict__ srcS,
                                                   const int* __restrict__ dstS,
                                                   float* __restrict__ agg, int E) {
    // Union: phase1 staging (ef bf16, 32768 B) / phase2 x-then-msg tile (64 x BSTRIDE bf16)
    __shared__ char smem[ROWS * BSTRIDE * 2];  // 33792 B, >= 32768
    __shared__ int permRow[ROWS];
    __shared__ int srcRow[ROWS];
    __shared__ int dstRow[ROWS];

    const int t = threadIdx.x;
    const int base = blockIdx.x * ROWS;
    const int rowsValid = min(ROWS, E - base);

    if (t < ROWS) {
        int gi = base + t;
        int gic = (gi < E) ? gi : (E - 1);
        permRow[t] = permS[gic];
        srcRow[t] = srcS[gic];
        dstRow[t] = (gi < E) ? dstS[gic] : -1;
    }
    __syncthreads();

    stage_rows_perm(ef, permRow, rowsValid, smem);
    __syncthreads();

    f32x4 acc[16];
#pragma unroll
    for (int i = 0; i < 16; ++i) acc[i] = (f32x4){0.f, 0.f, 0.f, 0.f};
    gemm_core(smem, We, acc);
    __syncthreads();   // all waves done reading staged ef; smem reusable

    // Stage x rows (bf16, 16B chunks): 64 rows x 32 chunks = 2048; 8 iters.
    ushort* xt = (ushort*)smem;   // [64][BSTRIDE]
#pragma unroll
    for (int i = 0; i < 8; ++i) {
        int c = i * 256 + t;
        int row = c >> 5;
        int col8 = (c & 31) << 3;
        int4 v = make_int4(0, 0, 0, 0);
        if (row < rowsValid)
            v = *(const int4*)(xbf + (size_t)srcRow[row] * DD + col8);
        *(int4*)(xt + row * BSTRIDE + col8) = v;
    }
    __syncthreads();

    const int lane = t & 63;
    const int wave = t >> 6;
    const int r = lane & 15, q = lane >> 4;
#pragma unroll
    for (int ct = 0; ct < 16; ++ct) {
        int col = ct * 16 + r;
        float bb = be[col];
#pragma unroll
        for (int j = 0; j < 4; ++j) {
            int lrow = wave * 16 + q * 4 + j;
            float y = mish_f(acc[ct][j] + bb);
            float xv = bf2f(xt[lrow * BSTRIDE + col]);
            float msg = (lrow < rowsValid) ? fmaxf(xv + y, 0.f) : 0.f;
            xt[lrow * BSTRIDE + col] = f2bf(msg);   // in-place: each slot owned by one thread
        }
    }
    __syncthreads();

    // Run-reduction: thread t owns col t; dst broadcast -> uniform branches.
    {
        int col = t;
        float run = 0.f;
        int dprev = dstRow[0];
        for (int r2 = 0; r2 < ROWS; ++r2) {
            int d = dstRow[r2];
            if (d != dprev) {
                if (dprev >= 0) atomicAdd(agg + (size_t)dprev * DD + col, run);
                run = 0.f;
                dprev = d;
            }
            run += bf2f(xt[r2 * BSTRIDE + col]);
        }
        if (dprev >= 0) atomicAdd(agg + (size_t)dprev * DD + col, run);
    }
}

// out = mish(agg @ Wo^T + bo), in place on agg (= d_out)
__global__ void __launch_bounds__(256) out_kernel(const ushort* __restrict__ Wo,
                                                  const float* __restrict__ bo,
                                                  float* __restrict__ agg_out, int M) {
    __shared__ char lds[ROWS * 512];
    const int base = blockIdx.x * ROWS;
    const int rowsValid = min(ROWS, M - base);
    stage_rows(agg_out + (size_t)base * DD, rowsValid, lds);
    __syncthreads();
    f32x4 acc[16];
#pragma unroll
    for (int i = 0; i < 16; ++i) acc[i] = (f32x4){0.f, 0.f, 0.f, 0.f};
    gemm_core(lds, Wo, acc);
    const int lane = threadIdx.x & 63;
    const int wave = threadIdx.x >> 6;
    const int r = lane & 15, q = lane >> 4;
#pragma unroll
    for (int ct = 0; ct < 16; ++ct) {
        int col = ct * 16 + r;
        float bb = bo[col];
#pragma unroll
        for (int j = 0; j < 4; ++j) {
            int lrow = wave * 16 + q * 4 + j;
            if (lrow < rowsValid) {
                size_t idx = (size_t)(base + lrow) * DD + col;
                agg_out[idx] = mish_f(acc[ct][j] + bb);
            }
        }
    }
}

extern "C" void kernel_launch(void* const* d_in, const int* in_sizes, int n_in,
                              void* d_out, int out_size, void* d_ws, size_t ws_size,
                              hipStream_t stream) {
    const float* nf = (const float*)d_in[0];
    const float* ef = (const float*)d_in[1];
    const int* src = (const int*)d_in[3];
    const int* dst = (const int*)d_in[4];
    const float* Wd = (const float*)d_in[5];
    const float* bd = (const float*)d_in[6];
    const float* We = (const float*)d_in[7];
    const float* be = (const float*)d_in[8];
    const float* Wo = (const float*)d_in[9];
    const float* bo = (const float*)d_in[10];

    const int M = in_sizes[0] / DD;   // 20000
    const int E = in_sizes[1] / DD;   // 320000
    float* out = (float*)d_out;       // agg: rst = x + sum(msg)

    auto align = [](size_t v) { return (v + 255) & ~(size_t)255; };
    char* ws = (char*)d_ws;
    size_t off = 0;
    ushort* xbf = (ushort*)(ws + off); off += align((size_t)M * DD * 2);
    ushort* Wdb = (ushort*)(ws + off); off += align((size_t)DD * DD * 2);
    ushort* Web = (ushort*)(ws + off); off += align((size_t)DD * DD * 2);
    ushort* Wob = (ushort*)(ws + off); off += align((size_t)DD * DD * 2);
    int* h     = (int*)(ws + off); off += align((size_t)M * 4);
    int* h2    = (int*)(ws + off); off += align((size_t)M * 4);
    int* permS = (int*)(ws + off); off += align((size_t)E * 4);
    int* srcS  = (int*)(ws + off); off += align((size_t)E * 4);
    int* dstS  = (int*)(ws + off); off += align((size_t)E * 4);

    const int n4 = DD * DD / 4;
    convert_w_kernel<<<(n4 + 255) / 256, 256, 0, stream>>>(Wd, Wdb, n4);
    convert_w_kernel<<<(n4 + 255) / 256, 256, 0, stream>>>(We, Web, n4);
    convert_w_kernel<<<(n4 + 255) / 256, 256, 0, stream>>>(Wo, Wob, n4);

    // Build dst-sorted edge order (counting sort)
    zero_kernel<<<(M + 255) / 256, 256, 0, stream>>>(h, M);
    hist_kernel<<<(E + 255) / 256, 256, 0, stream>>>(dst, h, E);
    scan_kernel<<<1, 256, 0, stream>>>(h, h2, M);
    scatter_kernel<<<(E + 255) / 256, 256, 0, stream>>>(src, dst, h2, permS, srcS, dstS, E);

    const int nwgN = (M + ROWS - 1) / ROWS;
    node_kernel<<<nwgN, 256, 0, stream>>>(nf, Wdb, bd, xbf, out, M);
    const int nwgE = (E + ROWS - 1) / ROWS;
    edge_kernel<<<nwgE, 256, 0, stream>>>(ef, Web, be, xbf, permS, srcS, dstS, out, E);
    out_kernel<<<nwgN, 256, 0, stream>>>(Wob, bo, out, M);
}

// Round 5
// 740.629 us; speedup vs baseline: 1.0093x; 1.0093x over previous
//
#include <hip/hip_runtime.h>
#include <hip/hip_bf16.h>

#define DD 256
#define ROWS 64
#define BSTRIDE 264   // bf16 elements per row in x/msg LDS tile (528 B, 16B-aligned)

typedef __attribute__((ext_vector_type(8))) short bf16x8;
typedef __attribute__((ext_vector_type(4))) float f32x4;

__device__ __forceinline__ ushort f2bf(float f) {
    unsigned u = __float_as_uint(f);
    u += 0x7fffu + ((u >> 16) & 1u);
    return (ushort)(u >> 16);
}
__device__ __forceinline__ float bf2f(ushort h) {
    return __uint_as_float(((unsigned)h) << 16);
}

__device__ __forceinline__ float mish_f(float t) {
    float u = __expf(t);
    float w = u * (u + 2.0f);
    float r = t * (w / (w + 2.0f));
    return (t > 15.0f) ? t : r;
}

// Stage up to 64 rows x 256 cols fp32 -> bf16 LDS, XOR-swizzled (row*512 + (kbyte ^ ((row&7)<<4))).
// Per wave-instruction: one 1KB contiguous row read (coalesced).
__device__ __forceinline__ void stage_rows(const float* __restrict__ src,
                                           int rowsValid, char* lds) {
    const int t = threadIdx.x;
#pragma unroll
    for (int i = 0; i < 16; ++i) {
        int c = i * 256 + t;
        int row = c >> 6;
        int col4 = (c & 63) << 2;
        float4 v = make_float4(0.f, 0.f, 0.f, 0.f);
        if (row < rowsValid)
            v = *(const float4*)(src + (size_t)row * DD + col4);
        ushort4 h;
        h.x = f2bf(v.x); h.y = f2bf(v.y); h.z = f2bf(v.z); h.w = f2bf(v.w);
        int off = row * 512 + ((col4 * 2) ^ ((row & 7) << 4));
        *(ushort4*)(lds + off) = h;
    }
}

__device__ __forceinline__ void stage_rows_perm(const float* __restrict__ src,
                                                const int* permRow, int rowsValid,
                                                char* lds) {
    const int t = threadIdx.x;
#pragma unroll
    for (int i = 0; i < 16; ++i) {
        int c = i * 256 + t;
        int row = c >> 6;
        int col4 = (c & 63) << 2;
        float4 v = make_float4(0.f, 0.f, 0.f, 0.f);
        if (row < rowsValid)
            v = *(const float4*)(src + (size_t)permRow[row] * DD + col4);
        ushort4 h;
        h.x = f2bf(v.x); h.y = f2bf(v.y); h.z = f2bf(v.z); h.w = f2bf(v.w);
        int off = row * 512 + ((col4 * 2) ^ ((row & 7) << 4));
        *(ushort4*)(lds + off) = h;
    }
}

// 64x256 @ W^T (256x256): 4 waves x 16 rows. A: row=lane&15, k=(lane>>4)*8+j.
// B is FRAGMENT-MAJOR: Wf[(ct*8+ks)*64 + lane] is the bf16x8 this lane needs
// -> every B load is 64 lanes x contiguous 16B = 1KB coalesced.
__device__ __forceinline__ void gemm_core(const char* lds, const ushort* __restrict__ Wf,
                                          f32x4 acc[16]) {
    const int lane = threadIdx.x & 63;
    const int wave = threadIdx.x >> 6;
    const int row = wave * 16 + (lane & 15);
    const int halfk = lane >> 4;
    bf16x8 afr[8];
#pragma unroll
    for (int ks = 0; ks < 8; ++ks) {
        int kbyte = ks * 64 + halfk * 16;
        afr[ks] = *(const bf16x8*)(lds + row * 512 + (kbyte ^ ((row & 7) << 4)));
    }
    const bf16x8* Wfrag = (const bf16x8*)Wf;
#pragma unroll
    for (int ct = 0; ct < 16; ++ct) {
#pragma unroll
        for (int ks = 0; ks < 8; ++ks) {
            bf16x8 bfr = Wfrag[(ct * 8 + ks) * 64 + lane];
            acc[ct] = __builtin_amdgcn_mfma_f32_16x16x32_bf16(afr[ks], bfr, acc[ct], 0, 0, 0);
        }
    }
}

// Repack W (DD x DD fp32 row-major) into fragment-major bf16:
// Wf[((ct*8+ks)*64+lane)*8 + j] = bf16( W[ct*16+(lane&15)][ks*32+(lane>>4)*8+j] )
__global__ void __launch_bounds__(256) convert_w_kernel(const float* __restrict__ in,
                                                        ushort* __restrict__ out, int nfrag) {
    int f = blockIdx.x * blockDim.x + threadIdx.x;
    if (f >= nfrag) return;
    int lane = f & 63;
    int ks = (f >> 6) & 7;
    int ct = f >> 9;
    int row = ct * 16 + (lane & 15);
    int kbase = ks * 32 + (lane >> 4) * 8;
    const float* p = in + (size_t)row * DD + kbase;
    float4 a = *(const float4*)p;
    float4 b = *(const float4*)(p + 4);
    ushort4 h0, h1;
    h0.x = f2bf(a.x); h0.y = f2bf(a.y); h0.z = f2bf(a.z); h0.w = f2bf(a.w);
    h1.x = f2bf(b.x); h1.y = f2bf(b.y); h1.z = f2bf(b.z); h1.w = f2bf(b.w);
    ushort4* o = (ushort4*)(out + (size_t)f * 8);
    o[0] = h0; o[1] = h1;
}

__global__ void __launch_bounds__(256) zero_kernel(int* __restrict__ p, int n) {
    int i = blockIdx.x * blockDim.x + threadIdx.x;
    if (i < n) p[i] = 0;
}

__global__ void __launch_bounds__(256) hist_kernel(const int* __restrict__ dst,
                                                   int* __restrict__ h, int E) {
    int e = blockIdx.x * blockDim.x + threadIdx.x;
    if (e < E) atomicAdd(&h[dst[e]], 1);
}

// Single-block exclusive scan: h[0..n) -> h2[0..n)
__global__ void __launch_bounds__(256) scan_kernel(const int* __restrict__ h,
                                                   int* __restrict__ h2, int n) {
    __shared__ int wsum[4];
    __shared__ int carry_s;
    if (threadIdx.x == 0) carry_s = 0;
    const int lane = threadIdx.x & 63;
    const int wave = threadIdx.x >> 6;
    for (int base = 0; base < n; base += 256) {
        int i = base + threadIdx.x;
        int v = (i < n) ? h[i] : 0;
        int s = v;
#pragma unroll
        for (int off = 1; off < 64; off <<= 1) {
            int u = __shfl_up(s, off, 64);
            if (lane >= off) s += u;
        }
        __syncthreads();
        if (lane == 63) wsum[wave] = s;
        __syncthreads();
        int prefix = carry_s;
        for (int wv = 0; wv < wave; ++wv) prefix += wsum[wv];
        if (i < n) h2[i] = prefix + s - v;   // exclusive
        __syncthreads();
        if (threadIdx.x == 0) carry_s += wsum[0] + wsum[1] + wsum[2] + wsum[3];
    }
}

__global__ void __launch_bounds__(256) scatter_kernel(const int* __restrict__ src,
                                                      const int* __restrict__ dst,
                                                      int* __restrict__ h2,
                                                      int* __restrict__ permS,
                                                      int* __restrict__ srcS,
                                                      int* __restrict__ dstS, int E) {
    int e = blockIdx.x * blockDim.x + threadIdx.x;
    if (e < E) {
        int d = dst[e];
        int pos = atomicAdd(&h2[d], 1);
        permS[pos] = e;
        srcS[pos] = src[e];
        dstS[pos] = d;
    }
}

// x = mish(node @ Wd^T + bd); write bf16 to xbf (ws) and f32 to agg (d_out)
__global__ void __launch_bounds__(256) node_kernel(const float* __restrict__ nf,
                                                   const ushort* __restrict__ Wd,
                                                   const float* __restrict__ bd,
                                                   ushort* __restrict__ xbf,
                                                   float* __restrict__ agg, int M) {
    __shared__ char lds[ROWS * 512];
    const int base = blockIdx.x * ROWS;
    const int rowsValid = min(ROWS, M - base);
    stage_rows(nf + (size_t)base * DD, rowsValid, lds);
    __syncthreads();
    f32x4 acc[16];
#pragma unroll
    for (int i = 0; i < 16; ++i) acc[i] = (f32x4){0.f, 0.f, 0.f, 0.f};
    gemm_core(lds, Wd, acc);
    const int lane = threadIdx.x & 63;
    const int wave = threadIdx.x >> 6;
    const int r = lane & 15, q = lane >> 4;
#pragma unroll
    for (int ct = 0; ct < 16; ++ct) {
        int col = ct * 16 + r;
        float bb = bd[col];
#pragma unroll
        for (int j = 0; j < 4; ++j) {
            int lrow = wave * 16 + q * 4 + j;
            if (lrow < rowsValid) {
                size_t idx = (size_t)(base + lrow) * DD + col;
                float m = mish_f(acc[ct][j] + bb);
                xbf[idx] = f2bf(m);
                agg[idx] = m;
            }
        }
    }
}

// Sorted-edge kernel: gather ef via perm, GEMM, msg = relu(x[src]+y) into LDS,
// run-reduce rows sharing dst, one atomicAdd per (run,col).
__global__ void __launch_bounds__(256) edge_kernel(const float* __restrict__ ef,
                                                   const ushort* __restrict__ We,
                                                   const float* __restrict__ be,
                                                   const ushort* __restrict__ xbf,
                                                   const int* __restrict__ permS,
                                                   const int* __restrict__ srcS,
                                                   const int* __restrict__ dstS,
                                                   float* __restrict__ agg, int E) {
    __shared__ char smem[ROWS * BSTRIDE * 2];  // 33792 B, >= 32768
    __shared__ int permRow[ROWS];
    __shared__ int srcRow[ROWS];
    __shared__ int dstRow[ROWS];

    const int t = threadIdx.x;
    const int base = blockIdx.x * ROWS;
    const int rowsValid = min(ROWS, E - base);

    if (t < ROWS) {
        int gi = base + t;
        int gic = (gi < E) ? gi : (E - 1);
        permRow[t] = permS[gic];
        srcRow[t] = srcS[gic];
        dstRow[t] = (gi < E) ? dstS[gic] : -1;
    }
    __syncthreads();

    stage_rows_perm(ef, permRow, rowsValid, smem);
    __syncthreads();

    f32x4 acc[16];
#pragma unroll
    for (int i = 0; i < 16; ++i) acc[i] = (f32x4){0.f, 0.f, 0.f, 0.f};
    gemm_core(smem, We, acc);
    __syncthreads();   // staged ef consumed; smem reusable

    // Stage x rows (bf16, 16B chunks): 64 rows x 32 chunks = 2048; 8 iters.
    ushort* xt = (ushort*)smem;   // [64][BSTRIDE]
#pragma unroll
    for (int i = 0; i < 8; ++i) {
        int c = i * 256 + t;
        int row = c >> 5;
        int col8 = (c & 31) << 3;
        int4 v = make_int4(0, 0, 0, 0);
        if (row < rowsValid)
            v = *(const int4*)(xbf + (size_t)srcRow[row] * DD + col8);
        *(int4*)(xt + row * BSTRIDE + col8) = v;
    }
    __syncthreads();

    const int lane = t & 63;
    const int wave = t >> 6;
    const int r = lane & 15, q = lane >> 4;
#pragma unroll
    for (int ct = 0; ct < 16; ++ct) {
        int col = ct * 16 + r;
        float bb = be[col];
#pragma unroll
        for (int j = 0; j < 4; ++j) {
            int lrow = wave * 16 + q * 4 + j;
            float y = mish_f(acc[ct][j] + bb);
            float xv = bf2f(xt[lrow * BSTRIDE + col]);
            float msg = (lrow < rowsValid) ? fmaxf(xv + y, 0.f) : 0.f;
            xt[lrow * BSTRIDE + col] = f2bf(msg);
        }
    }
    __syncthreads();

    // Run-reduction: thread t owns col t; dst broadcast -> uniform branches.
    {
        int col = t;
        float run = 0.f;
        int dprev = dstRow[0];
        for (int r2 = 0; r2 < ROWS; ++r2) {
            int d = dstRow[r2];
            if (d != dprev) {
                if (dprev >= 0) atomicAdd(agg + (size_t)dprev * DD + col, run);
                run = 0.f;
                dprev = d;
            }
            run += bf2f(xt[r2 * BSTRIDE + col]);
        }
        if (dprev >= 0) atomicAdd(agg + (size_t)dprev * DD + col, run);
    }
}

// out = mish(agg @ Wo^T + bo), in place on agg (= d_out)
__global__ void __launch_bounds__(256) out_kernel(const ushort* __restrict__ Wo,
                                                  const float* __restrict__ bo,
                                                  float* __restrict__ agg_out, int M) {
    __shared__ char lds[ROWS * 512];
    const int base = blockIdx.x * ROWS;
    const int rowsValid = min(ROWS, M - base);
    stage_rows(agg_out + (size_t)base * DD, rowsValid, lds);
    __syncthreads();
    f32x4 acc[16];
#pragma unroll
    for (int i = 0; i < 16; ++i) acc[i] = (f32x4){0.f, 0.f, 0.f, 0.f};
    gemm_core(lds, Wo, acc);
    const int lane = threadIdx.x & 63;
    const int wave = threadIdx.x >> 6;
    const int r = lane & 15, q = lane >> 4;
#pragma unroll
    for (int ct = 0; ct < 16; ++ct) {
        int col = ct * 16 + r;
        float bb = bo[col];
#pragma unroll
        for (int j = 0; j < 4; ++j) {
            int lrow = wave * 16 + q * 4 + j;
            if (lrow < rowsValid) {
                size_t idx = (size_t)(base + lrow) * DD + col;
                agg_out[idx] = mish_f(acc[ct][j] + bb);
            }
        }
    }
}

extern "C" void kernel_launch(void* const* d_in, const int* in_sizes, int n_in,
                              void* d_out, int out_size, void* d_ws, size_t ws_size,
                              hipStream_t stream) {
    const float* nf = (const float*)d_in[0];
    const float* ef = (const float*)d_in[1];
    const int* src = (const int*)d_in[3];
    const int* dst = (const int*)d_in[4];
    const float* Wd = (const float*)d_in[5];
    const float* bd = (const float*)d_in[6];
    const float* We = (const float*)d_in[7];
    const float* be = (const float*)d_in[8];
    const float* Wo = (const float*)d_in[9];
    const float* bo = (const float*)d_in[10];

    const int M = in_sizes[0] / DD;   // 20000
    const int E = in_sizes[1] / DD;   // 320000
    float* out = (float*)d_out;       // agg: rst = x + sum(msg)

    auto align = [](size_t v) { return (v + 255) & ~(size_t)255; };
    char* ws = (char*)d_ws;
    size_t off = 0;
    ushort* xbf = (ushort*)(ws + off); off += align((size_t)M * DD * 2);
    ushort* Wdb = (ushort*)(ws + off); off += align((size_t)DD * DD * 2);
    ushort* Web = (ushort*)(ws + off); off += align((size_t)DD * DD * 2);
    ushort* Wob = (ushort*)(ws + off); off += align((size_t)DD * DD * 2);
    int* h     = (int*)(ws + off); off += align((size_t)M * 4);
    int* h2    = (int*)(ws + off); off += align((size_t)M * 4);
    int* permS = (int*)(ws + off); off += align((size_t)E * 4);
    int* srcS  = (int*)(ws + off); off += align((size_t)E * 4);
    int* dstS  = (int*)(ws + off); off += align((size_t)E * 4);

    const int nfrag = (DD / 16) * (DD / 32) * 64;  // 8192 fragments per weight
    convert_w_kernel<<<(nfrag + 255) / 256, 256, 0, stream>>>(Wd, Wdb, nfrag);
    convert_w_kernel<<<(nfrag + 255) / 256, 256, 0, stream>>>(We, Web, nfrag);
    convert_w_kernel<<<(nfrag + 255) / 256, 256, 0, stream>>>(Wo, Wob, nfrag);

    // Build dst-sorted edge order (counting sort)
    zero_kernel<<<(M + 255) / 256, 256, 0, stream>>>(h, M);
    hist_kernel<<<(E + 255) / 256, 256, 0, stream>>>(dst, h, E);
    scan_kernel<<<1, 256, 0, stream>>>(h, h2, M);
    scatter_kernel<<<(E + 255) / 256, 256, 0, stream>>>(src, dst, h2, permS, srcS, dstS, E);

    const int nwgN = (M + ROWS - 1) / ROWS;
    node_kernel<<<nwgN, 256, 0, stream>>>(nf, Wdb, bd, xbf, out, M);
    const int nwgE = (E + ROWS - 1) / ROWS;
    edge_kernel<<<nwgE, 256, 0, stream>>>(ef, Web, be, xbf, permS, srcS, dstS, out, E);
    out_kernel<<<nwgN, 256, 0, stream>>>(Wob, bo, out, M);
}

// Round 6
// 396.896 us; speedup vs baseline: 1.8834x; 1.8661x over previous
//
#include <hip/hip_runtime.h>
#include <hip/hip_bf16.h>

#define DD 256
#define ROWS 64      // node/out tile
#define EROWS 32     // edge tile (round 6: halved for occupancy + shorter latency chains)
#define BSTRIDE 264  // bf16 elements per row in x/msg LDS tile (528 B, 16B-aligned)

typedef __attribute__((ext_vector_type(8))) short bf16x8;
typedef __attribute__((ext_vector_type(4))) float f32x4;

__device__ __forceinline__ ushort f2bf(float f) {
    unsigned u = __float_as_uint(f);
    u += 0x7fffu + ((u >> 16) & 1u);
    return (ushort)(u >> 16);
}
__device__ __forceinline__ float bf2f(ushort h) {
    return __uint_as_float(((unsigned)h) << 16);
}

__device__ __forceinline__ float mish_f(float t) {
    float u = __expf(t);
    float w = u * (u + 2.0f);
    float r = t * (w / (w + 2.0f));
    return (t > 15.0f) ? t : r;
}

// Stage up to 64 rows x 256 cols fp32 -> bf16 LDS, XOR-swizzled (row*512 + (kbyte ^ ((row&7)<<4))).
__device__ __forceinline__ void stage_rows(const float* __restrict__ src,
                                           int rowsValid, char* lds) {
    const int t = threadIdx.x;
#pragma unroll
    for (int i = 0; i < 16; ++i) {
        int c = i * 256 + t;
        int row = c >> 6;
        int col4 = (c & 63) << 2;
        float4 v = make_float4(0.f, 0.f, 0.f, 0.f);
        if (row < rowsValid)
            v = *(const float4*)(src + (size_t)row * DD + col4);
        ushort4 h;
        h.x = f2bf(v.x); h.y = f2bf(v.y); h.z = f2bf(v.z); h.w = f2bf(v.w);
        int off = row * 512 + ((col4 * 2) ^ ((row & 7) << 4));
        *(ushort4*)(lds + off) = h;
    }
}

// 64x256 @ W^T: 4 waves x 16 rows x 256 cols (node/out kernels).
// B fragment-major: Wf[(ct*8+ks)*64+lane] = contiguous 1KB wave-load.
__device__ __forceinline__ void gemm_core(const char* lds, const ushort* __restrict__ Wf,
                                          f32x4 acc[16]) {
    const int lane = threadIdx.x & 63;
    const int wave = threadIdx.x >> 6;
    const int row = wave * 16 + (lane & 15);
    const int halfk = lane >> 4;
    const bf16x8* Wfrag = (const bf16x8*)Wf;
#pragma unroll
    for (int ks = 0; ks < 8; ++ks) {
        int kbyte = ks * 64 + halfk * 16;
        bf16x8 a = *(const bf16x8*)(lds + row * 512 + (kbyte ^ ((row & 7) << 4)));
#pragma unroll
        for (int ct = 0; ct < 16; ++ct) {
            bf16x8 b = Wfrag[(ct * 8 + ks) * 64 + lane];
            acc[ct] = __builtin_amdgcn_mfma_f32_16x16x32_bf16(a, b, acc[ct], 0, 0, 0);
        }
    }
}

// Repack W (DD x DD fp32 row-major) into fragment-major bf16:
// Wf[((ct*8+ks)*64+lane)*8 + j] = bf16( W[ct*16+(lane&15)][ks*32+(lane>>4)*8+j] )
__global__ void __launch_bounds__(256) convert_w_kernel(const float* __restrict__ in,
                                                        ushort* __restrict__ out, int nfrag) {
    int f = blockIdx.x * blockDim.x + threadIdx.x;
    if (f >= nfrag) return;
    int lane = f & 63;
    int ks = (f >> 6) & 7;
    int ct = f >> 9;
    int row = ct * 16 + (lane & 15);
    int kbase = ks * 32 + (lane >> 4) * 8;
    const float* p = in + (size_t)row * DD + kbase;
    float4 a = *(const float4*)p;
    float4 b = *(const float4*)(p + 4);
    ushort4 h0, h1;
    h0.x = f2bf(a.x); h0.y = f2bf(a.y); h0.z = f2bf(a.z); h0.w = f2bf(a.w);
    h1.x = f2bf(b.x); h1.y = f2bf(b.y); h1.z = f2bf(b.z); h1.w = f2bf(b.w);
    ushort4* o = (ushort4*)(out + (size_t)f * 8);
    o[0] = h0; o[1] = h1;
}

__global__ void __launch_bounds__(256) zero_kernel(int* __restrict__ p, int n) {
    int i = blockIdx.x * blockDim.x + threadIdx.x;
    if (i < n) p[i] = 0;
}

__global__ void __launch_bounds__(256) hist_kernel(const int* __restrict__ dst,
                                                   int* __restrict__ h, int E) {
    int e = blockIdx.x * blockDim.x + threadIdx.x;
    if (e < E) atomicAdd(&h[dst[e]], 1);
}

// Single-block exclusive scan: h[0..n) -> h2[0..n)
__global__ void __launch_bounds__(256) scan_kernel(const int* __restrict__ h,
                                                   int* __restrict__ h2, int n) {
    __shared__ int wsum[4];
    __shared__ int carry_s;
    if (threadIdx.x == 0) carry_s = 0;
    const int lane = threadIdx.x & 63;
    const int wave = threadIdx.x >> 6;
    for (int base = 0; base < n; base += 256) {
        int i = base + threadIdx.x;
        int v = (i < n) ? h[i] : 0;
        int s = v;
#pragma unroll
        for (int off = 1; off < 64; off <<= 1) {
            int u = __shfl_up(s, off, 64);
            if (lane >= off) s += u;
        }
        __syncthreads();
        if (lane == 63) wsum[wave] = s;
        __syncthreads();
        int prefix = carry_s;
        for (int wv = 0; wv < wave; ++wv) prefix += wsum[wv];
        if (i < n) h2[i] = prefix + s - v;   // exclusive
        __syncthreads();
        if (threadIdx.x == 0) carry_s += wsum[0] + wsum[1] + wsum[2] + wsum[3];
    }
}

__global__ void __launch_bounds__(256) scatter_kernel(const int* __restrict__ src,
                                                      const int* __restrict__ dst,
                                                      int* __restrict__ h2,
                                                      int* __restrict__ permS,
                                                      int* __restrict__ srcS,
                                                      int* __restrict__ dstS, int E) {
    int e = blockIdx.x * blockDim.x + threadIdx.x;
    if (e < E) {
        int d = dst[e];
        int pos = atomicAdd(&h2[d], 1);
        permS[pos] = e;
        srcS[pos] = src[e];
        dstS[pos] = d;
    }
}

// x = mish(node @ Wd^T + bd); write bf16 to xbf (ws) and f32 to agg (d_out)
__global__ void __launch_bounds__(256) node_kernel(const float* __restrict__ nf,
                                                   const ushort* __restrict__ Wd,
                                                   const float* __restrict__ bd,
                                                   ushort* __restrict__ xbf,
                                                   float* __restrict__ agg, int M) {
    __shared__ char lds[ROWS * 512];
    const int base = blockIdx.x * ROWS;
    const int rowsValid = min(ROWS, M - base);
    stage_rows(nf + (size_t)base * DD, rowsValid, lds);
    __syncthreads();
    f32x4 acc[16];
#pragma unroll
    for (int i = 0; i < 16; ++i) acc[i] = (f32x4){0.f, 0.f, 0.f, 0.f};
    gemm_core(lds, Wd, acc);
    const int lane = threadIdx.x & 63;
    const int wave = threadIdx.x >> 6;
    const int r = lane & 15, q = lane >> 4;
#pragma unroll
    for (int ct = 0; ct < 16; ++ct) {
        int col = ct * 16 + r;
        float bb = bd[col];
#pragma unroll
        for (int j = 0; j < 4; ++j) {
            int lrow = wave * 16 + q * 4 + j;
            if (lrow < rowsValid) {
                size_t idx = (size_t)(base + lrow) * DD + col;
                float m = mish_f(acc[ct][j] + bb);
                xbf[idx] = f2bf(m);
                agg[idx] = m;
            }
        }
    }
}

// Sorted-edge kernel, 32-row tile: gather ef via perm (8 staging instrs), GEMM
// with 4 waves x (16 rows x 128 cols) N-split (64 B-loads/wave, batched 8/ks),
// msg = relu(x[src]+y) into LDS, 32-iter run-reduce, atomicAdd per (run,col).
__global__ void __launch_bounds__(256, 5) edge_kernel(const float* __restrict__ ef,
                                                      const ushort* __restrict__ We,
                                                      const float* __restrict__ be,
                                                      const ushort* __restrict__ xbf,
                                                      const int* __restrict__ permS,
                                                      const int* __restrict__ srcS,
                                                      const int* __restrict__ dstS,
                                                      float* __restrict__ agg, int E) {
    __shared__ char smem[EROWS * BSTRIDE * 2];  // 16896 B: staging (32*512 swz) / xt (32*528)
    __shared__ int permRow[EROWS];
    __shared__ int srcRow[EROWS];
    __shared__ int dstRow[EROWS];

    const int t = threadIdx.x;
    const int base = blockIdx.x * EROWS;
    const int rowsValid = min(EROWS, E - base);

    if (t < EROWS) {
        int gi = base + t;
        int gic = (gi < E) ? gi : (E - 1);
        permRow[t] = permS[gic];
        srcRow[t] = srcS[gic];
        dstRow[t] = (gi < E) ? dstS[gic] : -1;
    }
    __syncthreads();

    // Stage ef rows (32 x 256 fp32 -> bf16 swizzled): 8 x 1KB coalesced wave-loads.
#pragma unroll
    for (int i = 0; i < 8; ++i) {
        int c = i * 256 + t;
        int row = c >> 6;
        int col4 = (c & 63) << 2;
        float4 v = make_float4(0.f, 0.f, 0.f, 0.f);
        if (row < rowsValid)
            v = *(const float4*)(ef + (size_t)permRow[row] * DD + col4);
        ushort4 h;
        h.x = f2bf(v.x); h.y = f2bf(v.y); h.z = f2bf(v.z); h.w = f2bf(v.w);
        int off = row * 512 + ((col4 * 2) ^ ((row & 7) << 4));
        *(ushort4*)(smem + off) = h;
    }
    __syncthreads();

    // GEMM: wave w -> rows [(w>>1)*16, +16), cols [(w&1)*128, +128). acc[8] tiles.
    const int lane = t & 63;
    const int wave = t >> 6;
    const int rowBase = (wave >> 1) * 16;
    const int colBase = (wave & 1) * 128;
    const int r = lane & 15;
    const int halfk = lane >> 4;
    const int arow = rowBase + r;
    const int ctg0 = colBase >> 4;   // first ct tile index (0 or 8)

    f32x4 acc[8];
#pragma unroll
    for (int i = 0; i < 8; ++i) acc[i] = (f32x4){0.f, 0.f, 0.f, 0.f};
    const bf16x8* Wfrag = (const bf16x8*)We;
#pragma unroll
    for (int ks = 0; ks < 8; ++ks) {
        int kbyte = ks * 64 + halfk * 16;
        bf16x8 a = *(const bf16x8*)(smem + arow * 512 + (kbyte ^ ((arow & 7) << 4)));
#pragma unroll
        for (int ct = 0; ct < 8; ++ct) {
            bf16x8 b = Wfrag[((ctg0 + ct) * 8 + ks) * 64 + lane];
            acc[ct] = __builtin_amdgcn_mfma_f32_16x16x32_bf16(a, b, acc[ct], 0, 0, 0);
        }
    }
    __syncthreads();   // staged ef consumed; smem reusable

    // Stage x rows (32 x 256 bf16): 4 iters of int4 (2 x 512B segments per wave-load).
    ushort* xt = (ushort*)smem;   // [32][BSTRIDE]
#pragma unroll
    for (int i = 0; i < 4; ++i) {
        int c = i * 256 + t;
        int row = c >> 5;
        int col8 = (c & 31) << 3;
        int4 v = make_int4(0, 0, 0, 0);
        if (row < rowsValid)
            v = *(const int4*)(xbf + (size_t)srcRow[row] * DD + col8);
        *(int4*)(xt + row * BSTRIDE + col8) = v;
    }
    __syncthreads();

    // Epilogue: y = mish(acc + be); msg = relu(x + y) written in place over xt.
    const int q = lane >> 4;
#pragma unroll
    for (int ct = 0; ct < 8; ++ct) {
        int col = colBase + ct * 16 + r;
        float bb = be[col];
#pragma unroll
        for (int j = 0; j < 4; ++j) {
            int lrow = rowBase + q * 4 + j;
            float y = mish_f(acc[ct][j] + bb);
            float xv = bf2f(xt[lrow * BSTRIDE + col]);
            float msg = (lrow < rowsValid) ? fmaxf(xv + y, 0.f) : 0.f;
            xt[lrow * BSTRIDE + col] = f2bf(msg);
        }
    }
    __syncthreads();

    // Run-reduction: thread t owns col t; dst broadcast -> uniform branches.
    {
        int col = t;
        float run = 0.f;
        int dprev = dstRow[0];
        for (int r2 = 0; r2 < EROWS; ++r2) {
            int d = dstRow[r2];
            if (d != dprev) {
                if (dprev >= 0) atomicAdd(agg + (size_t)dprev * DD + col, run);
                run = 0.f;
                dprev = d;
            }
            run += bf2f(xt[r2 * BSTRIDE + col]);
        }
        if (dprev >= 0) atomicAdd(agg + (size_t)dprev * DD + col, run);
    }
}

// out = mish(agg @ Wo^T + bo), in place on agg (= d_out)
__global__ void __launch_bounds__(256) out_kernel(const ushort* __restrict__ Wo,
                                                  const float* __restrict__ bo,
                                                  float* __restrict__ agg_out, int M) {
    __shared__ char lds[ROWS * 512];
    const int base = blockIdx.x * ROWS;
    const int rowsValid = min(ROWS, M - base);
    stage_rows(agg_out + (size_t)base * DD, rowsValid, lds);
    __syncthreads();
    f32x4 acc[16];
#pragma unroll
    for (int i = 0; i < 16; ++i) acc[i] = (f32x4){0.f, 0.f, 0.f, 0.f};
    gemm_core(lds, Wo, acc);
    const int lane = threadIdx.x & 63;
    const int wave = threadIdx.x >> 6;
    const int r = lane & 15, q = lane >> 4;
#pragma unroll
    for (int ct = 0; ct < 16; ++ct) {
        int col = ct * 16 + r;
        float bb = bo[col];
#pragma unroll
        for (int j = 0; j < 4; ++j) {
            int lrow = wave * 16 + q * 4 + j;
            if (lrow < rowsValid) {
                size_t idx = (size_t)(base + lrow) * DD + col;
                agg_out[idx] = mish_f(acc[ct][j] + bb);
            }
        }
    }
}

extern "C" void kernel_launch(void* const* d_in, const int* in_sizes, int n_in,
                              void* d_out, int out_size, void* d_ws, size_t ws_size,
                              hipStream_t stream) {
    const float* nf = (const float*)d_in[0];
    const float* ef = (const float*)d_in[1];
    const int* src = (const int*)d_in[3];
    const int* dst = (const int*)d_in[4];
    const float* Wd = (const float*)d_in[5];
    const float* bd = (const float*)d_in[6];
    const float* We = (const float*)d_in[7];
    const float* be = (const float*)d_in[8];
    const float* Wo = (const float*)d_in[9];
    const float* bo = (const float*)d_in[10];

    const int M = in_sizes[0] / DD;   // 20000
    const int E = in_sizes[1] / DD;   // 320000
    float* out = (float*)d_out;       // agg: rst = x + sum(msg)

    auto align = [](size_t v) { return (v + 255) & ~(size_t)255; };
    char* ws = (char*)d_ws;
    size_t off = 0;
    ushort* xbf = (ushort*)(ws + off); off += align((size_t)M * DD * 2);
    ushort* Wdb = (ushort*)(ws + off); off += align((size_t)DD * DD * 2);
    ushort* Web = (ushort*)(ws + off); off += align((size_t)DD * DD * 2);
    ushort* Wob = (ushort*)(ws + off); off += align((size_t)DD * DD * 2);
    int* h     = (int*)(ws + off); off += align((size_t)M * 4);
    int* h2    = (int*)(ws + off); off += align((size_t)M * 4);
    int* permS = (int*)(ws + off); off += align((size_t)E * 4);
    int* srcS  = (int*)(ws + off); off += align((size_t)E * 4);
    int* dstS  = (int*)(ws + off); off += align((size_t)E * 4);

    const int nfrag = (DD / 16) * (DD / 32) * 64;  // 8192 fragments per weight
    convert_w_kernel<<<(nfrag + 255) / 256, 256, 0, stream>>>(Wd, Wdb, nfrag);
    convert_w_kernel<<<(nfrag + 255) / 256, 256, 0, stream>>>(We, Web, nfrag);
    convert_w_kernel<<<(nfrag + 255) / 256, 256, 0, stream>>>(Wo, Wob, nfrag);

    // Build dst-sorted edge order (counting sort)
    zero_kernel<<<(M + 255) / 256, 256, 0, stream>>>(h, M);
    hist_kernel<<<(E + 255) / 256, 256, 0, stream>>>(dst, h, E);
    scan_kernel<<<1, 256, 0, stream>>>(h, h2, M);
    scatter_kernel<<<(E + 255) / 256, 256, 0, stream>>>(src, dst, h2, permS, srcS, dstS, E);

    const int nwgN = (M + ROWS - 1) / ROWS;
    node_kernel<<<nwgN, 256, 0, stream>>>(nf, Wdb, bd, xbf, out, M);
    const int nwgE = (E + EROWS - 1) / EROWS;
    edge_kernel<<<nwgE, 256, 0, stream>>>(ef, Web, be, xbf, permS, srcS, dstS, out, E);
    out_kernel<<<nwgN, 256, 0, stream>>>(Wob, bo, out, M);
}